// Round 6
// baseline (462.335 us; speedup 1.0000x reference)
//
#include <hip/hip_runtime.h>

typedef __bf16 bf16_t;
typedef __bf16 bf16x8 __attribute__((ext_vector_type(8)));
typedef __bf16 bf16x4 __attribute__((ext_vector_type(4)));
typedef float f32x4 __attribute__((ext_vector_type(4)));

#define SEQL 2048
#define DIMM 4096
#define NH 32
#define NKV 8
#define HD 128

__device__ __forceinline__ void gl2lds16(const void* g, void* l) {
  __builtin_amdgcn_global_load_lds((__attribute__((address_space(1))) void*)g,
                                   (__attribute__((address_space(3))) void*)l,
                                   16, 0, 0);
}

// ---------------- fused fp32 -> bf16 convert of all 5 tensors ----------------
__global__ __launch_bounds__(256) void cvt5_kernel(const float* __restrict__ s0,
                                                   const float* __restrict__ s1,
                                                   const float* __restrict__ s2,
                                                   const float* __restrict__ s3,
                                                   const float* __restrict__ s4,
                                                   bf16_t* __restrict__ dst) {
  const long base = (long)blockIdx.x * 4096;
  const float* s;
  long o;
  if (base < 8388608L)       { s = s0; o = base; }
  else if (base < 25165824L) { s = s1; o = base - 8388608L; }
  else if (base < 29360128L) { s = s2; o = base - 25165824L; }
  else if (base < 33554432L) { s = s3; o = base - 29360128L; }
  else                       { s = s4; o = base - 33554432L; }
  const long t4 = threadIdx.x * 4;
#pragma unroll
  for (int j = 0; j < 4; ++j) {
    const long e = t4 + j * 1024;
    float4 v = *(const float4*)(s + o + e);
    bf16x4 ov;
    ov[0] = (bf16_t)v.x; ov[1] = (bf16_t)v.y; ov[2] = (bf16_t)v.z; ov[3] = (bf16_t)v.w;
    *(bf16x4*)(dst + base + e) = ov;
  }
}

// ---------------- QKV GEMM: 128x128 tile, 3-slot counted-vmcnt ring ----------
// Independent-block overlap (3 blocks/CU, 12 waves) + counted vmcnt(4) ring
// (no vmcnt(0) drain in the K-loop). BK=32; LDS = 3 slots x (A 8KB + B 8KB)
// = 48 KB -> 3 blocks/CU. Per tile: {8 ds_read_b128 | stage t+2 (4 gl_lds) |
// barrier | lgkm(0) | 16 MFMA | vmcnt(4) | barrier}.
// Epilogue (proven 111us version): C -> LDS (stride 136) -> RMSNorm+RoPE (Q/K)
// or transposed write (V). Q gets scale*log2(e) folded for the attn exp2.
#define TS 136
#define QSCALE (0.08838834764831845f * 1.4426950408889634f)
__global__ __launch_bounds__(256, 3) void gemm_qkv_kernel(const bf16_t* __restrict__ A,
                                                          const bf16_t* __restrict__ B,
                                                          const float* __restrict__ qnw,
                                                          const float* __restrict__ knw,
                                                          const float* __restrict__ rope,
                                                          const int* __restrict__ pos,
                                                          bf16_t* __restrict__ Qb,
                                                          bf16_t* __restrict__ Kb,
                                                          bf16_t* __restrict__ Vb) {
  __shared__ __align__(16) bf16_t smem[24576];  // 48 KiB: A ring | B ring @+12288
  const int K = DIMM;
  const int NT = K / 32;  // 128 K-tiles
  const int tid = threadIdx.x;
  const int lin = blockIdx.x;
  const int xcd = lin & 7, idx = lin >> 3;
  const int bm = (idx & 15) * 128;
  const int bn = ((idx >> 4) + xcd * 6) * 128;
  const int lane = tid & 63, wave = tid >> 6;
  const int wm = (wave >> 1) * 64, wn = (wave & 1) * 64;
  const int lr = lane & 15, quad = lane >> 4;
  const int swz = (quad ^ ((lr >> 1) & 3)) << 3;  // read-side k-group swizzle

  // staging: 1024 chunks of 16B per tile (A 512 + B 512); 4 gl_lds/thread.
  // chunk id: row=id>>2, kgrp=id&3; LDS dest linear; global k pre-swizzled
  // so the read-side XOR recovers k=quad*8 (verified structure, round 5).
  long src0, src1;
  int dst0, dst1;
  {
    const int id0 = tid, id1 = tid + 256;
    src0 = (long)(id0 >> 2) * K + (((id0 & 3) ^ ((id0 >> 3) & 3)) << 3);
    src1 = (long)(id1 >> 2) * K + (((id1 & 3) ^ ((id1 >> 3) & 3)) << 3);
    dst0 = id0 * 8;
    dst1 = id1 * 8;
  }
  const bf16_t* Abase = A + (long)bm * K;
  const bf16_t* Bbase = B + (long)bn * K;

  f32x4 acc[4][4];
#pragma unroll
  for (int mi = 0; mi < 4; ++mi)
#pragma unroll
    for (int ni = 0; ni < 4; ++ni)
      acc[mi][ni] = (f32x4){0.f, 0.f, 0.f, 0.f};

#define STG(sl_, t_)                                                  \
  do {                                                                \
    const long k0_ = (long)(t_) * 32;                                 \
    gl2lds16(Abase + src0 + k0_, smem + (sl_) * 4096 + dst0);         \
    gl2lds16(Abase + src1 + k0_, smem + (sl_) * 4096 + dst1);         \
    gl2lds16(Bbase + src0 + k0_, smem + 12288 + (sl_) * 4096 + dst0); \
    gl2lds16(Bbase + src1 + k0_, smem + 12288 + (sl_) * 4096 + dst1); \
  } while (0)

  // prologue: tiles 0,1 in flight; wait tile 0 only (tile 1 stays flying)
  STG(0, 0); STG(1, 1);
  asm volatile("s_waitcnt vmcnt(4)" ::: "memory");
  __builtin_amdgcn_s_barrier();

  int rs = 0, ss = 2;  // read slot (tile t), stage slot (tile t+2); t%3
  for (int t = 0; t < NT; ++t) {
    const bf16_t* As = smem + rs * 4096;
    const bf16_t* Bs = smem + 12288 + rs * 4096;
    bf16x8 af[4], bfr[4];
#pragma unroll
    for (int mi = 0; mi < 4; ++mi)
      af[mi] = *(const bf16x8*)&As[(wm + mi * 16 + lr) * 32 + swz];
#pragma unroll
    for (int ni = 0; ni < 4; ++ni)
      bfr[ni] = *(const bf16x8*)&Bs[(wn + ni * 16 + lr) * 32 + swz];
    if (t + 2 < NT) STG(ss, t + 2);
    __builtin_amdgcn_s_barrier();
    asm volatile("s_waitcnt lgkmcnt(0)" ::: "memory");
    __builtin_amdgcn_sched_barrier(0);
    __builtin_amdgcn_s_setprio(1);
#pragma unroll
    for (int mi = 0; mi < 4; ++mi)
#pragma unroll
      for (int ni = 0; ni < 4; ++ni)
        acc[mi][ni] = __builtin_amdgcn_mfma_f32_16x16x32_bf16(af[mi], bfr[ni], acc[mi][ni], 0, 0, 0);
    __builtin_amdgcn_s_setprio(0);
    // counted wait: tile t+1 landed; tile t+2's 4 loads stay in flight
    if (t + 2 < NT) { asm volatile("s_waitcnt vmcnt(4)" ::: "memory"); }
    else            { asm volatile("s_waitcnt vmcnt(0)" ::: "memory"); }
    __builtin_amdgcn_s_barrier();
    rs = (rs == 2) ? 0 : rs + 1;
    ss = (ss == 2) ? 0 : ss + 1;
  }
#undef STG

  // ---- epilogue: C-tile -> LDS (bf16, stride TS) ----
  __syncthreads();
  bf16_t* tile = smem;
#pragma unroll
  for (int mi = 0; mi < 4; ++mi)
#pragma unroll
    for (int ni = 0; ni < 4; ++ni)
#pragma unroll
      for (int r = 0; r < 4; ++r)
        tile[(wm + mi * 16 + quad * 4 + r) * TS + wn + ni * 16 + lr] = (bf16_t)acc[mi][ni][r];
  __syncthreads();

  if (bn < 5120) {  // ---- Q or K head: RMSNorm + RoPE, write [h][s][128] ----
    const bool isQ = bn < 4096;
    const float* nwp = isQ ? qnw : knw;
    const float osc = isQ ? QSCALE : 1.0f;
    bf16_t* outp = isQ ? (Qb + (long)(bn >> 7) * SEQL * HD)
                       : (Kb + (long)((bn - 4096) >> 7) * SEQL * HD);
    const int r = tid >> 1, hf = tid & 1;
    bf16x8 rowv[16];
#pragma unroll
    for (int j = 0; j < 16; ++j) rowv[j] = *(const bf16x8*)&tile[r * TS + j * 8];
    float ss2 = 0.f;
#pragma unroll
    for (int j = 0; j < 16; ++j)
#pragma unroll
      for (int e = 0; e < 8; ++e) { const float f = (float)rowv[j][e]; ss2 += f * f; }
    const float sc = rsqrtf(ss2 * (1.0f / 128.0f) + 1e-6f) * osc;
    const int p = pos[bm + r];
    const float* rp = rope + p * 128;
    bf16_t obuf[64];
#pragma unroll
    for (int g = 0; g < 8; ++g) {
#pragma unroll
      for (int e = 0; e < 8; ++e) {
        const int i = g * 8 + e;
        const float2 cs = *(const float2*)(rp + 2 * i);
        const float nlo = (float)rowv[i >> 3][i & 7] * sc * nwp[i];
        const float nhi = (float)rowv[8 + (i >> 3)][i & 7] * sc * nwp[64 + i];
        obuf[i] = (bf16_t)(hf ? (nhi * cs.x + nlo * cs.y) : (nlo * cs.x - nhi * cs.y));
      }
    }
    bf16_t* op = outp + (long)(bm + r) * HD + hf * 64;
#pragma unroll
    for (int g = 0; g < 8; ++g) *(bf16x8*)(op + g * 8) = *(const bf16x8*)&obuf[g * 8];
  } else {  // ---- V head: transposed write [hk][d][s] ----
    const int hk = (bn - 5120) >> 7;
    const int d = tid & 127, shalf = tid >> 7;
    bf16_t* vp = Vb + ((long)hk * HD + d) * SEQL + bm + shalf * 64;
#pragma unroll
    for (int grp = 0; grp < 8; ++grp) {
      bf16x8 tv;
#pragma unroll
      for (int e = 0; e < 8; ++e) tv[e] = tile[(shalf * 64 + grp * 8 + e) * TS + d];
      *(bf16x8*)(vp + grp * 8) = tv;
    }
  }
}

// ---------------- O-projection NT GEMM: same 3-slot ring, fp32 out ----------
template <typename CT>
__global__ __launch_bounds__(256, 3) void gemm_bt_kernel(const bf16_t* __restrict__ A,
                                                         const bf16_t* __restrict__ B,
                                                         CT* __restrict__ C,
                                                         int N, int K, int npanel) {
  __shared__ __align__(16) bf16_t smem[24576];
  const int NT = K >> 5;
  const int tid = threadIdx.x;
  const int lin = blockIdx.x;
  const int xcd = lin & 7, idx = lin >> 3;
  const int bm = (idx & 15) * 128;
  const int bn = ((idx >> 4) + xcd * npanel) * 128;
  const int lane = tid & 63, wave = tid >> 6;
  const int wm = (wave >> 1) * 64, wn = (wave & 1) * 64;
  const int lr = lane & 15, quad = lane >> 4;
  const int swz = (quad ^ ((lr >> 1) & 3)) << 3;

  long src0, src1;
  int dst0, dst1;
  {
    const int id0 = tid, id1 = tid + 256;
    src0 = (long)(id0 >> 2) * K + (((id0 & 3) ^ ((id0 >> 3) & 3)) << 3);
    src1 = (long)(id1 >> 2) * K + (((id1 & 3) ^ ((id1 >> 3) & 3)) << 3);
    dst0 = id0 * 8;
    dst1 = id1 * 8;
  }
  const bf16_t* Abase = A + (long)bm * K;
  const bf16_t* Bbase = B + (long)bn * K;

  f32x4 acc[4][4];
#pragma unroll
  for (int mi = 0; mi < 4; ++mi)
#pragma unroll
    for (int ni = 0; ni < 4; ++ni)
      acc[mi][ni] = (f32x4){0.f, 0.f, 0.f, 0.f};

#define STG(sl_, t_)                                                  \
  do {                                                                \
    const long k0_ = (long)(t_) * 32;                                 \
    gl2lds16(Abase + src0 + k0_, smem + (sl_) * 4096 + dst0);         \
    gl2lds16(Abase + src1 + k0_, smem + (sl_) * 4096 + dst1);         \
    gl2lds16(Bbase + src0 + k0_, smem + 12288 + (sl_) * 4096 + dst0); \
    gl2lds16(Bbase + src1 + k0_, smem + 12288 + (sl_) * 4096 + dst1); \
  } while (0)

  STG(0, 0); STG(1, 1);
  asm volatile("s_waitcnt vmcnt(4)" ::: "memory");
  __builtin_amdgcn_s_barrier();

  int rs = 0, ss = 2;
  for (int t = 0; t < NT; ++t) {
    const bf16_t* As = smem + rs * 4096;
    const bf16_t* Bs = smem + 12288 + rs * 4096;
    bf16x8 af[4], bfr[4];
#pragma unroll
    for (int mi = 0; mi < 4; ++mi)
      af[mi] = *(const bf16x8*)&As[(wm + mi * 16 + lr) * 32 + swz];
#pragma unroll
    for (int ni = 0; ni < 4; ++ni)
      bfr[ni] = *(const bf16x8*)&Bs[(wn + ni * 16 + lr) * 32 + swz];
    if (t + 2 < NT) STG(ss, t + 2);
    __builtin_amdgcn_s_barrier();
    asm volatile("s_waitcnt lgkmcnt(0)" ::: "memory");
    __builtin_amdgcn_sched_barrier(0);
    __builtin_amdgcn_s_setprio(1);
#pragma unroll
    for (int mi = 0; mi < 4; ++mi)
#pragma unroll
      for (int ni = 0; ni < 4; ++ni)
        acc[mi][ni] = __builtin_amdgcn_mfma_f32_16x16x32_bf16(af[mi], bfr[ni], acc[mi][ni], 0, 0, 0);
    __builtin_amdgcn_s_setprio(0);
    if (t + 2 < NT) { asm volatile("s_waitcnt vmcnt(4)" ::: "memory"); }
    else            { asm volatile("s_waitcnt vmcnt(0)" ::: "memory"); }
    __builtin_amdgcn_s_barrier();
    rs = (rs == 2) ? 0 : rs + 1;
    ss = (ss == 2) ? 0 : ss + 1;
  }
#undef STG

#pragma unroll
  for (int mi = 0; mi < 4; ++mi) {
    const int row = bm + wm + mi * 16 + quad * 4;
#pragma unroll
    for (int ni = 0; ni < 4; ++ni) {
      const int col = bn + wn + ni * 16 + lr;
      CT* cp = C + (long)row * N + col;
#pragma unroll
      for (int r = 0; r < 4; ++r) cp[(long)r * N] = (CT)acc[mi][ni][r];
    }
  }
}

// ---------------- flash attention, block-diag causal, FIXED-RANGE softmax ----
#define CK 64
#define PSTR 72
__global__ __launch_bounds__(256) void attn_kernel(const bf16_t* __restrict__ Q,
                                                   const bf16_t* __restrict__ Kt,
                                                   const bf16_t* __restrict__ Vt,
                                                   bf16_t* __restrict__ O) {
  __shared__ bf16_t lK[CK * 128];    // [kk][d]
  __shared__ bf16_t lV[144 * CK];    // [d][kk]; rows 128..143 = ones (l trick)
  __shared__ bf16_t lP[128 * PSTR];  // [m][kk]
  const int lin = blockIdx.x;
  const int qb = (lin < 256) ? (3 - (lin & 1)) : (lin & 1);
  const int gh = (lin >> 1) & 127;
  const int h = gh & 31, g = gh >> 5;
  const int hk = h >> 2;
  const int tid = threadIdx.x, lane = tid & 63, wave = tid >> 6;
  const int lr = lane & 15, quad = lane >> 4;
  const int s_base = g * 512 + qb * 128;

  if (tid < 128) {
    bf16x8 one8;
#pragma unroll
    for (int j = 0; j < 8; ++j) one8[j] = (bf16_t)1.0f;
    *(bf16x8*)&lV[128 * CK + tid * 8] = one8;
  }

  bf16x8 qf[2][4];
  const bf16_t* Qp = Q + ((long)h * SEQL + s_base + wave * 32 + lr) * HD + quad * 8;
#pragma unroll
  for (int mi = 0; mi < 2; ++mi)
#pragma unroll
    for (int ks = 0; ks < 4; ++ks)
      qf[mi][ks] = *(const bf16x8*)(Qp + mi * 16 * HD + ks * 32);

  f32x4 oacc[2][9];
#pragma unroll
  for (int mi = 0; mi < 2; ++mi)
#pragma unroll
    for (int di = 0; di < 9; ++di) oacc[mi][di] = (f32x4){0.f, 0.f, 0.f, 0.f};

  const int nchunk = 2 * qb + 2;
  for (int c = 0; c < nchunk; ++c) {
    __syncthreads();
    {
      const bf16_t* Kg = Kt + ((long)hk * SEQL + g * 512 + c * CK) * HD;
      const bf16_t* Vg = Vt + (long)hk * HD * SEQL + g * 512 + c * CK;
#pragma unroll
      for (int cc = 0; cc < 4; ++cc) {
        const int i = tid + 256 * cc;
        gl2lds16(Kg + (long)(i >> 4) * HD + (i & 15) * 8, lK + i * 8);
        gl2lds16(Vg + (long)(i >> 3) * SEQL + (i & 7) * 8, lV + i * 8);
      }
    }
    __syncthreads();

    f32x4 sv[2][4];
#pragma unroll
    for (int mi = 0; mi < 2; ++mi)
#pragma unroll
      for (int ni = 0; ni < 4; ++ni) sv[mi][ni] = (f32x4){0.f, 0.f, 0.f, 0.f};
#pragma unroll
    for (int ks = 0; ks < 4; ++ks) {
#pragma unroll
      for (int ni = 0; ni < 4; ++ni) {
        const bf16x8 kf = *(const bf16x8*)&lK[(ni * 16 + lr) * 128 + ks * 32 + quad * 8];
        sv[0][ni] = __builtin_amdgcn_mfma_f32_16x16x32_bf16(qf[0][ks], kf, sv[0][ni], 0, 0, 0);
        sv[1][ni] = __builtin_amdgcn_mfma_f32_16x16x32_bf16(qf[1][ks], kf, sv[1][ni], 0, 0, 0);
      }
    }

#pragma unroll
    for (int mi = 0; mi < 2; ++mi)
#pragma unroll
      for (int ni = 0; ni < 4; ++ni)
#pragma unroll
        for (int r = 0; r < 4; ++r) {
          const int colseg = c * CK + ni * 16 + lr;
          const int rowseg = qb * 128 + wave * 32 + mi * 16 + quad * 4 + r;
          float p = exp2f(sv[mi][ni][r]);
          p = (colseg > rowseg) ? 0.f : p;
          lP[(wave * 32 + mi * 16 + quad * 4 + r) * PSTR + ni * 16 + lr] = (bf16_t)p;
        }
    __syncthreads();

#pragma unroll
    for (int ks = 0; ks < 2; ++ks) {
      const bf16x8 pf0 = *(const bf16x8*)&lP[(wave * 32 + lr) * PSTR + ks * 32 + quad * 8];
      const bf16x8 pf1 = *(const bf16x8*)&lP[(wave * 32 + 16 + lr) * PSTR + ks * 32 + quad * 8];
#pragma unroll
      for (int di = 0; di < 9; ++di) {
        const bf16x8 vfr = *(const bf16x8*)&lV[(di * 16 + lr) * CK + ks * 32 + quad * 8];
        oacc[0][di] = __builtin_amdgcn_mfma_f32_16x16x32_bf16(pf0, vfr, oacc[0][di], 0, 0, 0);
        oacc[1][di] = __builtin_amdgcn_mfma_f32_16x16x32_bf16(pf1, vfr, oacc[1][di], 0, 0, 0);
      }
    }
  }

#pragma unroll
  for (int mi = 0; mi < 2; ++mi)
#pragma unroll
    for (int r = 0; r < 4; ++r) {
      const float inv = 1.0f / oacc[mi][8][r];
      const int row = s_base + wave * 32 + mi * 16 + quad * 4 + r;
      bf16_t* opp = O + (long)row * DIMM + h * HD + lr;
#pragma unroll
      for (int di = 0; di < 8; ++di) opp[di * 16] = (bf16_t)(oacc[mi][di][r] * inv);
    }
}

// -----------------------------------------------------------------------------
extern "C" void kernel_launch(void* const* d_in, const int* in_sizes, int n_in,
                              void* d_out, int out_size, void* d_ws, size_t ws_size,
                              hipStream_t stream) {
  (void)in_sizes; (void)n_in; (void)out_size; (void)ws_size;
  const float* x    = (const float*)d_in[0];
  const float* wq   = (const float*)d_in[1];
  const float* wk   = (const float*)d_in[2];
  const float* wv   = (const float*)d_in[3];
  const float* wo   = (const float*)d_in[4];
  const float* qnw  = (const float*)d_in[5];
  const float* knw  = (const float*)d_in[6];
  const float* rope = (const float*)d_in[7];
  const int*   pos  = (const int*)d_in[8];
  float* out = (float*)d_out;

  char* ws = (char*)d_ws;
  size_t off = 0;
  auto alloc = [&](size_t b) { char* p = ws + off; off += (b + 255) & ~(size_t)255; return p; };
  bf16_t* xb    = (bf16_t*)alloc((size_t)SEQL * DIMM * 2);
  bf16_t* wqkvb = (bf16_t*)alloc((size_t)DIMM * DIMM * 2);
  alloc((size_t)NKV * HD * DIMM * 2);
  alloc((size_t)NKV * HD * DIMM * 2);
  bf16_t* wob   = (bf16_t*)alloc((size_t)DIMM * DIMM * 2);
  bf16_t* Qb    = (bf16_t*)alloc((size_t)NH * SEQL * HD * 2);
  bf16_t* Kb    = (bf16_t*)alloc((size_t)NKV * SEQL * HD * 2);
  bf16_t* Vb    = (bf16_t*)alloc((size_t)NKV * SEQL * HD * 2);
  bf16_t* attnb = xb;  // xb dead after QKV GEMM

  cvt5_kernel<<<dim3(12288), 256, 0, stream>>>(x, wq, wk, wv, wo, xb);
  gemm_qkv_kernel<<<dim3(768), 256, 0, stream>>>(xb, wqkvb, qnw, knw, rope, pos, Qb, Kb, Vb);
  attn_kernel<<<dim3(512), 256, 0, stream>>>(Qb, Kb, Vb, attnb);
  gemm_bt_kernel<float><<<dim3(512), 256, 0, stream>>>(attnb, wob, out, DIMM, DIMM, 4);
}

// Round 7
// 425.415 us; speedup vs baseline: 1.0868x; 1.0868x over previous
//
#include <hip/hip_runtime.h>

typedef __bf16 bf16_t;
typedef __bf16 bf16x8 __attribute__((ext_vector_type(8)));
typedef __bf16 bf16x4 __attribute__((ext_vector_type(4)));
typedef float f32x4 __attribute__((ext_vector_type(4)));

#define SEQL 2048
#define DIMM 4096
#define NH 32
#define NKV 8
#define HD 128

__device__ __forceinline__ void gl2lds16(const void* g, void* l) {
  __builtin_amdgcn_global_load_lds((__attribute__((address_space(1))) void*)g,
                                   (__attribute__((address_space(3))) void*)l,
                                   16, 0, 0);
}

// ---------------- fused fp32 -> bf16 convert of all 5 tensors ----------------
__global__ __launch_bounds__(256) void cvt5_kernel(const float* __restrict__ s0,
                                                   const float* __restrict__ s1,
                                                   const float* __restrict__ s2,
                                                   const float* __restrict__ s3,
                                                   const float* __restrict__ s4,
                                                   bf16_t* __restrict__ dst) {
  const long base = (long)blockIdx.x * 4096;
  const float* s;
  long o;
  if (base < 8388608L)       { s = s0; o = base; }
  else if (base < 25165824L) { s = s1; o = base - 8388608L; }
  else if (base < 29360128L) { s = s2; o = base - 25165824L; }
  else if (base < 33554432L) { s = s3; o = base - 29360128L; }
  else                       { s = s4; o = base - 33554432L; }
  const long t4 = threadIdx.x * 4;
#pragma unroll
  for (int j = 0; j < 4; ++j) {
    const long e = t4 + j * 1024;
    float4 v = *(const float4*)(s + o + e);
    bf16x4 ov;
    ov[0] = (bf16_t)v.x; ov[1] = (bf16_t)v.y; ov[2] = (bf16_t)v.z; ov[3] = (bf16_t)v.w;
    *(bf16x4*)(dst + base + e) = ov;
  }
}

// ---------------- QKV GEMM with fused RMSNorm+RoPE+V-transpose epilogue ------
// Round-0 verified kernel (111us, MfmaUtil 40%, FETCH 96MB). BK=64 keeps the
// staging reads full-128B-line per row (BK=32 ring doubled FETCH, round 6).
#define TS 136
#define QSCALE (0.08838834764831845f * 1.4426950408889634f)
__global__ __launch_bounds__(256, 3) void gemm_qkv_kernel(const bf16_t* __restrict__ A,
                                                          const bf16_t* __restrict__ B,
                                                          const float* __restrict__ qnw,
                                                          const float* __restrict__ knw,
                                                          const float* __restrict__ rope,
                                                          const int* __restrict__ pos,
                                                          bf16_t* __restrict__ Qb,
                                                          bf16_t* __restrict__ Kb,
                                                          bf16_t* __restrict__ Vb) {
  __shared__ __align__(16) bf16_t smem[128 * TS];  // 34816 B; carved: lA | lB
  bf16_t* lA = smem;
  bf16_t* lB = smem + 8192;
  const int K = DIMM, npanel = 6;
  const int tid = threadIdx.x;
  const int lin = blockIdx.x;
  const int xcd = lin & 7, idx = lin >> 3;
  const int bm = (idx & 15) * 128;
  const int bn = ((idx >> 4) + xcd * npanel) * 128;
  const int lane = tid & 63, wave = tid >> 6;
  const int wm = (wave >> 1) * 64, wn = (wave & 1) * 64;
  const int lr = lane & 15, quad = lane >> 4;

  f32x4 acc[4][4];
#pragma unroll
  for (int mi = 0; mi < 4; ++mi)
#pragma unroll
    for (int ni = 0; ni < 4; ++ni)
      acc[mi][ni] = (f32x4){0.f, 0.f, 0.f, 0.f};

  long soff[4];
#pragma unroll
  for (int c = 0; c < 4; ++c) {
    const int s = tid + 256 * c;
    soff[c] = (long)(s >> 3) * K + (((s & 7) ^ ((s >> 3) & 7)) << 3);
  }
  const bf16_t* Abase = A + (long)bm * K;
  const bf16_t* Bbase = B + (long)bn * K;

  for (int k0 = 0; k0 < K; k0 += 64) {
    __syncthreads();
#pragma unroll
    for (int c = 0; c < 4; ++c) {
      gl2lds16(Abase + soff[c] + k0, lA + (tid + 256 * c) * 8);
      gl2lds16(Bbase + soff[c] + k0, lB + (tid + 256 * c) * 8);
    }
    __syncthreads();
#pragma unroll
    for (int ks = 0; ks < 2; ++ks) {
      bf16x8 af[4], bfr[4];
#pragma unroll
      for (int mi = 0; mi < 4; ++mi)
        af[mi] = *(const bf16x8*)&lA[(wm + mi * 16 + lr) * 64 + ((((ks << 2) | quad) ^ (lr & 7)) << 3)];
#pragma unroll
      for (int ni = 0; ni < 4; ++ni)
        bfr[ni] = *(const bf16x8*)&lB[(wn + ni * 16 + lr) * 64 + ((((ks << 2) | quad) ^ (lr & 7)) << 3)];
#pragma unroll
      for (int mi = 0; mi < 4; ++mi)
#pragma unroll
        for (int ni = 0; ni < 4; ++ni)
          acc[mi][ni] = __builtin_amdgcn_mfma_f32_16x16x32_bf16(af[mi], bfr[ni], acc[mi][ni], 0, 0, 0);
    }
  }

  // ---- epilogue: C-tile -> LDS (bf16, stride TS) ----
  __syncthreads();  // all waves done reading lA/lB
  bf16_t* tile = smem;
#pragma unroll
  for (int mi = 0; mi < 4; ++mi)
#pragma unroll
    for (int ni = 0; ni < 4; ++ni)
#pragma unroll
      for (int r = 0; r < 4; ++r)
        tile[(wm + mi * 16 + quad * 4 + r) * TS + wn + ni * 16 + lr] = (bf16_t)acc[mi][ni][r];
  __syncthreads();

  if (bn < 5120) {  // ---- Q or K head: RMSNorm + RoPE, write [h][s][128] ----
    const bool isQ = bn < 4096;
    const float* nwp = isQ ? qnw : knw;
    const float osc = isQ ? QSCALE : 1.0f;
    bf16_t* outp = isQ ? (Qb + (long)(bn >> 7) * SEQL * HD)
                       : (Kb + (long)((bn - 4096) >> 7) * SEQL * HD);
    const int r = tid >> 1, hf = tid & 1;
    bf16x8 rowv[16];
#pragma unroll
    for (int j = 0; j < 16; ++j) rowv[j] = *(const bf16x8*)&tile[r * TS + j * 8];
    float ss = 0.f;
#pragma unroll
    for (int j = 0; j < 16; ++j)
#pragma unroll
      for (int e = 0; e < 8; ++e) { const float f = (float)rowv[j][e]; ss += f * f; }
    const float sc = rsqrtf(ss * (1.0f / 128.0f) + 1e-6f) * osc;
    const int p = pos[bm + r];
    const float* rp = rope + p * 128;
    bf16_t obuf[64];
#pragma unroll
    for (int g = 0; g < 8; ++g) {
#pragma unroll
      for (int e = 0; e < 8; ++e) {
        const int i = g * 8 + e;
        const float2 cs = *(const float2*)(rp + 2 * i);
        const float nlo = (float)rowv[i >> 3][i & 7] * sc * nwp[i];
        const float nhi = (float)rowv[8 + (i >> 3)][i & 7] * sc * nwp[64 + i];
        obuf[i] = (bf16_t)(hf ? (nhi * cs.x + nlo * cs.y) : (nlo * cs.x - nhi * cs.y));
      }
    }
    bf16_t* op = outp + (long)(bm + r) * HD + hf * 64;
#pragma unroll
    for (int g = 0; g < 8; ++g) *(bf16x8*)(op + g * 8) = *(const bf16x8*)&obuf[g * 8];
  } else {  // ---- V head: transposed write [hk][d][s] ----
    const int hk = (bn - 5120) >> 7;
    const int d = tid & 127, shalf = tid >> 7;
    bf16_t* vp = Vb + ((long)hk * HD + d) * SEQL + bm + shalf * 64;
#pragma unroll
    for (int grp = 0; grp < 8; ++grp) {
      bf16x8 t;
#pragma unroll
      for (int e = 0; e < 8; ++e) t[e] = tile[(shalf * 64 + grp * 8 + e) * TS + d];
      *(bf16x8*)(vp + grp * 8) = t;
    }
  }
}

// ---------------- plain NT GEMM (O-projection): C[M,N] = A @ B^T, fp32 out ---
template <typename CT>
__global__ __launch_bounds__(256, 3) void gemm_bt_kernel(const bf16_t* __restrict__ A,
                                                         const bf16_t* __restrict__ B,
                                                         CT* __restrict__ C,
                                                         int N, int K, int npanel) {
  __shared__ bf16_t lA[128 * 64];
  __shared__ bf16_t lB[128 * 64];
  const int tid = threadIdx.x;
  const int lin = blockIdx.x;
  const int xcd = lin & 7, idx = lin >> 3;
  const int bm = (idx & 15) * 128;
  const int bn = ((idx >> 4) + xcd * npanel) * 128;
  const int lane = tid & 63, wave = tid >> 6;
  const int wm = (wave >> 1) * 64, wn = (wave & 1) * 64;
  const int lr = lane & 15, quad = lane >> 4;

  f32x4 acc[4][4];
#pragma unroll
  for (int mi = 0; mi < 4; ++mi)
#pragma unroll
    for (int ni = 0; ni < 4; ++ni)
      acc[mi][ni] = (f32x4){0.f, 0.f, 0.f, 0.f};

  long soff[4];
#pragma unroll
  for (int c = 0; c < 4; ++c) {
    const int s = tid + 256 * c;
    soff[c] = (long)(s >> 3) * K + (((s & 7) ^ ((s >> 3) & 7)) << 3);
  }
  const bf16_t* Abase = A + (long)bm * K;
  const bf16_t* Bbase = B + (long)bn * K;

  for (int k0 = 0; k0 < K; k0 += 64) {
    __syncthreads();
#pragma unroll
    for (int c = 0; c < 4; ++c) {
      gl2lds16(Abase + soff[c] + k0, lA + (tid + 256 * c) * 8);
      gl2lds16(Bbase + soff[c] + k0, lB + (tid + 256 * c) * 8);
    }
    __syncthreads();
#pragma unroll
    for (int ks = 0; ks < 2; ++ks) {
      bf16x8 af[4], bfr[4];
#pragma unroll
      for (int mi = 0; mi < 4; ++mi)
        af[mi] = *(const bf16x8*)&lA[(wm + mi * 16 + lr) * 64 + ((((ks << 2) | quad) ^ (lr & 7)) << 3)];
#pragma unroll
      for (int ni = 0; ni < 4; ++ni)
        bfr[ni] = *(const bf16x8*)&lB[(wn + ni * 16 + lr) * 64 + ((((ks << 2) | quad) ^ (lr & 7)) << 3)];
#pragma unroll
      for (int mi = 0; mi < 4; ++mi)
#pragma unroll
        for (int ni = 0; ni < 4; ++ni)
          acc[mi][ni] = __builtin_amdgcn_mfma_f32_16x16x32_bf16(af[mi], bfr[ni], acc[mi][ni], 0, 0, 0);
    }
  }

#pragma unroll
  for (int mi = 0; mi < 4; ++mi) {
    const int row = bm + wm + mi * 16 + quad * 4;
#pragma unroll
    for (int ni = 0; ni < 4; ++ni) {
      const int col = bn + wn + ni * 16 + lr;
      CT* cp = C + (long)row * N + col;
#pragma unroll
      for (int r = 0; r < 4; ++r) cp[(long)r * N] = (CT)acc[mi][ni][r];
    }
  }
}

// ---------------- flash attention, block-diag causal, FIXED-RANGE softmax ----
// K double-buffered + counted vmcnt: per chunk issue V(c),K(c+1); vmcnt(8)
// gates QK^T (K(c) landed, K(c+1)+V(c) in flight); vmcnt(4) gates PV (V(c)
// landed under QK^T+softmax). V single-buffered (PV must finish before V(c+1)
// issue -> loop-top barrier). nchunk >= 2 always, so c==0 is never the tail.
#define CK 64
#define PSTR 72
__global__ __launch_bounds__(256) void attn_kernel(const bf16_t* __restrict__ Q,
                                                   const bf16_t* __restrict__ Kt,
                                                   const bf16_t* __restrict__ Vt,
                                                   bf16_t* __restrict__ O) {
  __shared__ bf16_t lK[2 * CK * 128];  // 2 x [kk][d] (32KB)
  __shared__ bf16_t lV[144 * CK];      // [d][kk]; rows 128..143 = ones (l trick)
  __shared__ bf16_t lP[128 * PSTR];    // [m][kk]
  const int lin = blockIdx.x;
  const int qb = (lin < 256) ? (3 - (lin & 1)) : (lin & 1);
  const int gh = (lin >> 1) & 127;
  const int h = gh & 31, g = gh >> 5;
  const int hk = h >> 2;
  const int tid = threadIdx.x, lane = tid & 63, wave = tid >> 6;
  const int lr = lane & 15, quad = lane >> 4;
  const int s_base = g * 512 + qb * 128;

  if (tid < 128) {
    bf16x8 one8;
#pragma unroll
    for (int j = 0; j < 8; ++j) one8[j] = (bf16_t)1.0f;
    *(bf16x8*)&lV[128 * CK + tid * 8] = one8;
  }

  bf16x8 qf[2][4];
  const bf16_t* Qp = Q + ((long)h * SEQL + s_base + wave * 32 + lr) * HD + quad * 8;
#pragma unroll
  for (int mi = 0; mi < 2; ++mi)
#pragma unroll
    for (int ks = 0; ks < 4; ++ks)
      qf[mi][ks] = *(const bf16x8*)(Qp + mi * 16 * HD + ks * 32);

  f32x4 oacc[2][9];
#pragma unroll
  for (int mi = 0; mi < 2; ++mi)
#pragma unroll
    for (int di = 0; di < 9; ++di) oacc[mi][di] = (f32x4){0.f, 0.f, 0.f, 0.f};

  const bf16_t* Kg0 = Kt + ((long)hk * SEQL + g * 512) * HD;
  const bf16_t* Vg0 = Vt + (long)hk * HD * SEQL + g * 512;

#define STGK(c_, buf_)                                                        \
  do {                                                                        \
    const bf16_t* Kg = Kg0 + (long)(c_) * CK * HD;                            \
    _Pragma("unroll")                                                         \
    for (int cc = 0; cc < 4; ++cc) {                                          \
      const int i = tid + 256 * cc;                                           \
      gl2lds16(Kg + (long)(i >> 4) * HD + (i & 15) * 8,                       \
               lK + (buf_) * (CK * 128) + i * 8);                             \
    }                                                                         \
  } while (0)
#define STGV(c_)                                                              \
  do {                                                                        \
    const bf16_t* Vg = Vg0 + (long)(c_) * CK;                                 \
    _Pragma("unroll")                                                         \
    for (int cc = 0; cc < 4; ++cc) {                                          \
      const int i = tid + 256 * cc;                                           \
      gl2lds16(Vg + (long)(i >> 3) * SEQL + (i & 7) * 8, lV + i * 8);         \
    }                                                                         \
  } while (0)

  const int nchunk = 2 * qb + 2;
  // prologue: K(0) then V(0) in flight (order matters for the vmcnt ledger)
  STGK(0, 0);
  STGV(0);

  for (int c = 0; c < nchunk; ++c) {
    __syncthreads();  // prev PV done reading lV/lP; lV(c) overwrite now safe
    if (c > 0) STGV(c);
    if (c + 1 < nchunk) STGK(c + 1, (c + 1) & 1);
    // gate QK^T on K(c): steady out = K(c)4 + V(c)4 + K(c+1)4 -> vmcnt(8);
    // tail (no K(c+1)): out = K(c)4 + V(c)4 -> vmcnt(4).
    if (c + 1 < nchunk) { asm volatile("s_waitcnt vmcnt(8)" ::: "memory"); }
    else                { asm volatile("s_waitcnt vmcnt(4)" ::: "memory"); }
    __syncthreads();  // K(c) visible block-wide

    const bf16_t* lKc = lK + (c & 1) * (CK * 128);
    f32x4 sv[2][4];
#pragma unroll
    for (int mi = 0; mi < 2; ++mi)
#pragma unroll
      for (int ni = 0; ni < 4; ++ni) sv[mi][ni] = (f32x4){0.f, 0.f, 0.f, 0.f};
    __builtin_amdgcn_s_setprio(1);
#pragma unroll
    for (int ks = 0; ks < 4; ++ks) {
#pragma unroll
      for (int ni = 0; ni < 4; ++ni) {
        const bf16x8 kf = *(const bf16x8*)&lKc[(ni * 16 + lr) * 128 + ks * 32 + quad * 8];
        sv[0][ni] = __builtin_amdgcn_mfma_f32_16x16x32_bf16(qf[0][ks], kf, sv[0][ni], 0, 0, 0);
        sv[1][ni] = __builtin_amdgcn_mfma_f32_16x16x32_bf16(qf[1][ks], kf, sv[1][ni], 0, 0, 0);
      }
    }
    __builtin_amdgcn_s_setprio(0);

    // p = exp2(s) (scale folded into Q), mask, straight to LDS in A-layout
#pragma unroll
    for (int mi = 0; mi < 2; ++mi)
#pragma unroll
      for (int ni = 0; ni < 4; ++ni)
#pragma unroll
        for (int r = 0; r < 4; ++r) {
          const int colseg = c * CK + ni * 16 + lr;
          const int rowseg = qb * 128 + wave * 32 + mi * 16 + quad * 4 + r;
          float p = exp2f(sv[mi][ni][r]);
          p = (colseg > rowseg) ? 0.f : p;
          lP[(wave * 32 + mi * 16 + quad * 4 + r) * PSTR + ni * 16 + lr] = (bf16_t)p;
        }
    // gate PV on V(c): steady out = V(c)4 + K(c+1)4 -> vmcnt(4); tail -> 0.
    if (c + 1 < nchunk) { asm volatile("s_waitcnt vmcnt(4)" ::: "memory"); }
    else                { asm volatile("s_waitcnt vmcnt(0)" ::: "memory"); }
    __syncthreads();  // V(c) + P visible block-wide

    // O += P @ [V ; ones] (di=8 accumulates the row-sum l)
    __builtin_amdgcn_s_setprio(1);
#pragma unroll
    for (int ks = 0; ks < 2; ++ks) {
      const bf16x8 pf0 = *(const bf16x8*)&lP[(wave * 32 + lr) * PSTR + ks * 32 + quad * 8];
      const bf16x8 pf1 = *(const bf16x8*)&lP[(wave * 32 + 16 + lr) * PSTR + ks * 32 + quad * 8];
#pragma unroll
      for (int di = 0; di < 9; ++di) {
        const bf16x8 vfr = *(const bf16x8*)&lV[(di * 16 + lr) * CK + ks * 32 + quad * 8];
        oacc[0][di] = __builtin_amdgcn_mfma_f32_16x16x32_bf16(pf0, vfr, oacc[0][di], 0, 0, 0);
        oacc[1][di] = __builtin_amdgcn_mfma_f32_16x16x32_bf16(pf1, vfr, oacc[1][di], 0, 0, 0);
      }
    }
    __builtin_amdgcn_s_setprio(0);
  }
#undef STGK
#undef STGV

  // epilogue: O[s][h*128+d] = oacc/l
#pragma unroll
  for (int mi = 0; mi < 2; ++mi)
#pragma unroll
    for (int r = 0; r < 4; ++r) {
      const float inv = 1.0f / oacc[mi][8][r];
      const int row = s_base + wave * 32 + mi * 16 + quad * 4 + r;
      bf16_t* opp = O + (long)row * DIMM + h * HD + lr;
#pragma unroll
      for (int di = 0; di < 8; ++di) opp[di * 16] = (bf16_t)(oacc[mi][di][r] * inv);
    }
}

// -----------------------------------------------------------------------------
extern "C" void kernel_launch(void* const* d_in, const int* in_sizes, int n_in,
                              void* d_out, int out_size, void* d_ws, size_t ws_size,
                              hipStream_t stream) {
  (void)in_sizes; (void)n_in; (void)out_size; (void)ws_size;
  const float* x    = (const float*)d_in[0];
  const float* wq   = (const float*)d_in[1];
  const float* wk   = (const float*)d_in[2];
  const float* wv   = (const float*)d_in[3];
  const float* wo   = (const float*)d_in[4];
  const float* qnw  = (const float*)d_in[5];
  const float* knw  = (const float*)d_in[6];
  const float* rope = (const float*)d_in[7];
  const int*   pos  = (const int*)d_in[8];
  float* out = (float*)d_out;

  char* ws = (char*)d_ws;
  size_t off = 0;
  auto alloc = [&](size_t b) { char* p = ws + off; off += (b + 255) & ~(size_t)255; return p; };
  bf16_t* xb    = (bf16_t*)alloc((size_t)SEQL * DIMM * 2);
  bf16_t* wqkvb = (bf16_t*)alloc((size_t)DIMM * DIMM * 2);
  alloc((size_t)NKV * HD * DIMM * 2);
  alloc((size_t)NKV * HD * DIMM * 2);
  bf16_t* wob   = (bf16_t*)alloc((size_t)DIMM * DIMM * 2);
  bf16_t* Qb    = (bf16_t*)alloc((size_t)NH * SEQL * HD * 2);
  bf16_t* Kb    = (bf16_t*)alloc((size_t)NKV * SEQL * HD * 2);
  bf16_t* Vb    = (bf16_t*)alloc((size_t)NKV * SEQL * HD * 2);
  bf16_t* attnb = xb;  // xb dead after QKV GEMM

  cvt5_kernel<<<dim3(12288), 256, 0, stream>>>(x, wq, wk, wv, wo, xb);
  gemm_qkv_kernel<<<dim3(768), 256, 0, stream>>>(xb, wqkvb, qnw, knw, rope, pos, Qb, Kb, Vb);
  attn_kernel<<<dim3(512), 256, 0, stream>>>(Qb, Kb, Vb, attnb);
  gemm_bt_kernel<float><<<dim3(512), 256, 0, stream>>>(attnb, wob, out, DIMM, DIMM, 4);
}